// Round 3
// baseline (583.605 us; speedup 1.0000x reference)
//
#include <hip/hip_runtime.h>
#include <hip/hip_cooperative_groups.h>
#include <math.h>

namespace cg = cooperative_groups;

#define W 4096
#define S 4096
#define NK_MAX 1024
#define NBLK 1024   // 4 blocks/CU x 256 CUs -> cooperative-resident by construction

typedef float v4f __attribute__((ext_vector_type(4)));  // clang vector — valid for nontemporal builtins

// ---------------------------------------------------------------------------
// ws layout (floats):
//   [0,     8192)  : key table float2[4096]  (cos,sin) of 2*pi*k/4096
//   [8192, 16384)  : nm    float2[4096]  (noisy_mix, interleaved re/im)
//   [16384,17408)  : corr  float[1024]
// ---------------------------------------------------------------------------
// Single cooperative kernel, 3 phases with 2 grid syncs:
//   P1 nm (wave-per-row, no LDS/syncs) -> P2 corr (block-per-key)
//   -> P3 softmax-once + wave-per-row clean_key + NT-streamed output.
// ---------------------------------------------------------------------------

__global__ __launch_bounds__(256, 4) void fused_kernel(
    const float* __restrict__ hr, const float* __restrict__ hi,
    const float* __restrict__ cr, const float* __restrict__ ci,
    const int* __restrict__ nkp,
    float2* __restrict__ table, float2* __restrict__ nm,
    float* __restrict__ corr, float* __restrict__ out)
{
    cg::grid_group grid = cg::this_grid();
    const int bid = blockIdx.x;
    const int t = threadIdx.x;
    const int lane = t & 63, wid = t >> 6;

    __shared__ float s0[4], s1[4];
    __shared__ float red[8];
    __shared__ float satt[NK_MAX];  // unnormalized softmax weights

    const v4f* hr4 = (const v4f*)hr;
    const v4f* hi4 = (const v4f*)hi;
    const v4f* cr4 = (const v4f*)cr;
    const v4f* ci4 = (const v4f*)ci;

    // table entries for this block (4 of 4096): fp64 sincos of small phase ->
    // exact; hidden under the phase-1 row loads of the other waves.
    if (t < 4) {
        int k = bid * 4 + t;
        double theta = (double)k * (6.283185307179586 / (double)W);
        table[k] = make_float2((float)cos(theta), (float)sin(theta));
    }

    // ---- phase 1: nm[w] = sum_s holo[w,s]*conj(cue[w,s]); one wave per row.
    // 4 chunks x 4 float4 per array per lane; pure shuffle reduce, no LDS.
    // cue is single-use -> NT loads keep holo L3-resident for phase 3.
    {
        int w = bid * 4 + wid;
        size_t base = (size_t)w * 1024;  // 1024 float4 per row
        v4f vr = {0.f, 0.f, 0.f, 0.f}, vi = {0.f, 0.f, 0.f, 0.f};
#pragma unroll 1
        for (int ch = 0; ch < 4; ch++) {
            v4f a[4], b[4], c[4], d[4];
#pragma unroll
            for (int k = 0; k < 4; k++) {
                size_t i = base + ch * 256 + k * 64 + lane;
                a[k] = hr4[i];
                b[k] = hi4[i];
                c[k] = __builtin_nontemporal_load(&cr4[i]);
                d[k] = __builtin_nontemporal_load(&ci4[i]);
            }
            // (hr + i*hi)(cr - i*ci): re = hr*cr + hi*ci ; im = hi*cr - hr*ci
#pragma unroll
            for (int k = 0; k < 4; k++) {
                vr += a[k] * c[k] + b[k] * d[k];
                vi += b[k] * c[k] - a[k] * d[k];
            }
        }
        float sr = vr.x + vr.y + vr.z + vr.w;
        float si = vi.x + vi.y + vi.z + vi.w;
        for (int off = 32; off; off >>= 1) {
            sr += __shfl_down(sr, off);
            si += __shfl_down(si, off);
        }
        if (lane == 0) nm[w] = make_float2(sr, si);
    }

    grid.sync();

    // ---- phase 2: correlations[n] = |sum_w keys[n,w]*nm[w]|, block-per-key.
    int nk = *nkp;
    if (bid < nk) {
        int f = bid + 1;
        float sr = 0.f, si = 0.f;
        for (int w = t; w < W; w += 256) {
            int idx = (w * f) & (W - 1);
            float2 tt = table[idx];
            float2 v = nm[w];
            sr += tt.x * v.x - tt.y * v.y;
            si += tt.x * v.y + tt.y * v.x;
        }
        for (int off = 32; off; off >>= 1) {
            sr += __shfl_down(sr, off);
            si += __shfl_down(si, off);
        }
        if (lane == 0) { s0[wid] = sr; s1[wid] = si; }
        __syncthreads();
        if (t == 0) {
            float r = s0[0] + s0[1] + s0[2] + s0[3];
            float m = s1[0] + s1[1] + s1[2] + s1[3];
            corr[bid] = sqrtf(r * r + m * m);
        }
    }

    grid.sync();

    // ---- phase 3: block softmax (once, amortized over 4 rows) ----
    float v[4];
    float vmax = -INFINITY;
#pragma unroll
    for (int j = 0; j < 4; j++) {
        int i = t + j * 256;
        v[j] = (i < nk) ? corr[i] * 50.0f : -INFINITY;
        vmax = fmaxf(vmax, v[j]);
    }
    for (int off = 32; off; off >>= 1) vmax = fmaxf(vmax, __shfl_down(vmax, off));
    if (lane == 0) red[wid] = vmax;
    __syncthreads();
    float M = fmaxf(fmaxf(red[0], red[1]), fmaxf(red[2], red[3]));

    float esum = 0.f;
#pragma unroll
    for (int j = 0; j < 4; j++) {
        int i = t + j * 256;
        float e = (i < nk) ? expf(v[j] - M) : 0.f;
        satt[i] = e;  // unnormalized; divide by SUM at the end (linear op)
        esum += e;
    }
    for (int off = 32; off; off >>= 1) esum += __shfl_down(esum, off);
    if (lane == 0) red[4 + wid] = esum;
    __syncthreads();  // satt + red visible
    float SUM = red[4] + red[5] + red[6] + red[7];

    // ---- clean_key for this wave's row + stream the row (wave-independent) --
    {
        int w = bid * 4 + wid;
        size_t base = (size_t)w * 1024;
        const size_t total4 = (size_t)W * S / 4;

        float crr = 0.f, cii = 0.f;
#pragma unroll 4
        for (int k = 0; k < 16; k++) {
            int n = lane + k * 64;
            int idx = (w * (n + 1)) & (W - 1);
            float2 tt = table[idx];   // L1-hot 32 KB
            float a = satt[n];
            crr += a * tt.x;
            cii += a * tt.y;
        }
        for (int off = 32; off; off >>= 1) {
            crr += __shfl_down(crr, off);
            cii += __shfl_down(cii, off);
        }
        float ckr = __shfl(crr, 0) / SUM;
        float cki = __shfl(cii, 0) / SUM;

        // out[0,w,s] = hr*ckr - hi*cki ; out[1,w,s] = hr*cki + hi*ckr
        // NT stores: output written once, never re-read on device.
#pragma unroll 1
        for (int ch = 0; ch < 4; ch++) {
            v4f a[4], b[4];
#pragma unroll
            for (int k = 0; k < 4; k++) {
                size_t i = base + ch * 256 + k * 64 + lane;
                a[k] = hr4[i];
                b[k] = hi4[i];
            }
#pragma unroll
            for (int k = 0; k < 4; k++) {
                size_t i = base + ch * 256 + k * 64 + lane;
                v4f re = a[k] * ckr - b[k] * cki;
                v4f im = a[k] * cki + b[k] * ckr;
                __builtin_nontemporal_store(re, &((v4f*)out)[i]);
                __builtin_nontemporal_store(im, &((v4f*)out)[i + total4]);
            }
        }
    }
}

// ---------------------------------------------------------------------------
// Fallback (non-cooperative) chain — only used if the cooperative launch is
// rejected. Identical to the round-2 verified kernels.
// ---------------------------------------------------------------------------
__global__ void nm_kernel(const float* __restrict__ hr, const float* __restrict__ hi,
                          const float* __restrict__ cr, const float* __restrict__ ci,
                          float2* __restrict__ nm, float2* __restrict__ table) {
    int w = blockIdx.x;
    int t = threadIdx.x;
    size_t base = (size_t)w * 1024;
    const v4f* hr4 = (const v4f*)hr;
    const v4f* hi4 = (const v4f*)hi;
    const v4f* cr4 = (const v4f*)cr;
    const v4f* ci4 = (const v4f*)ci;

    v4f a[4], b[4], c[4], d[4];
#pragma unroll
    for (int k = 0; k < 4; k++) {
        size_t i = base + t + k * 256;
        a[k] = hr4[i];
        b[k] = hi4[i];
        c[k] = __builtin_nontemporal_load(&cr4[i]);
        d[k] = __builtin_nontemporal_load(&ci4[i]);
    }
    if (t == 0) {
        double theta = (double)w * (6.283185307179586 / (double)W);
        table[w] = make_float2((float)cos(theta), (float)sin(theta));
    }
    v4f vr = {0.f,0.f,0.f,0.f}, vi = {0.f,0.f,0.f,0.f};
#pragma unroll
    for (int k = 0; k < 4; k++) {
        vr += a[k] * c[k] + b[k] * d[k];
        vi += b[k] * c[k] - a[k] * d[k];
    }
    float sr = vr.x + vr.y + vr.z + vr.w;
    float si = vi.x + vi.y + vi.z + vi.w;
    for (int off = 32; off; off >>= 1) {
        sr += __shfl_down(sr, off);
        si += __shfl_down(si, off);
    }
    __shared__ float s0[4], s1[4];
    int lane = t & 63, wid = t >> 6;
    if (lane == 0) { s0[wid] = sr; s1[wid] = si; }
    __syncthreads();
    if (t == 0)
        nm[w] = make_float2(s0[0]+s0[1]+s0[2]+s0[3], s1[0]+s1[1]+s1[2]+s1[3]);
}

__global__ void corr_kernel(const float2* __restrict__ nm, const float2* __restrict__ table,
                            float* __restrict__ corr, const int* __restrict__ nkp) {
    int n = blockIdx.x;
    if (n >= *nkp) return;
    int f = n + 1;
    float sr = 0.f, si = 0.f;
    for (int w = threadIdx.x; w < W; w += 256) {
        int idx = (w * f) & (W - 1);
        float2 t = table[idx];
        float2 v = nm[w];
        sr += t.x * v.x - t.y * v.y;
        si += t.x * v.y + t.y * v.x;
    }
    for (int off = 32; off; off >>= 1) {
        sr += __shfl_down(sr, off);
        si += __shfl_down(si, off);
    }
    __shared__ float s0[4], s1[4];
    int lane = threadIdx.x & 63, wid = threadIdx.x >> 6;
    if (lane == 0) { s0[wid] = sr; s1[wid] = si; }
    __syncthreads();
    if (threadIdx.x == 0) {
        float r = s0[0] + s0[1] + s0[2] + s0[3];
        float m = s1[0] + s1[1] + s1[2] + s1[3];
        corr[n] = sqrtf(r * r + m * m);
    }
}

__global__ void out_kernel(const float* __restrict__ hr, const float* __restrict__ hi,
                           const float* __restrict__ corr, const float2* __restrict__ table,
                           const int* __restrict__ nkp, float* __restrict__ out) {
    int w = blockIdx.x;
    int t = threadIdx.x;
    size_t base = (size_t)w * 1024;
    const size_t total4 = (size_t)W * S / 4;
    int lane = t & 63, wid = t >> 6;
    __shared__ float red[8];

    v4f a[4], b[4];
#pragma unroll
    for (int k = 0; k < 4; k++) {
        size_t i = base + t + k * 256;
        a[k] = ((const v4f*)hr)[i];
        b[k] = ((const v4f*)hi)[i];
    }
    int nk = *nkp;

    float v[4];
    float vmax = -INFINITY;
#pragma unroll
    for (int j = 0; j < 4; j++) {
        int i = t + j * 256;
        v[j] = (i < nk) ? corr[i] * 50.0f : -INFINITY;
        vmax = fmaxf(vmax, v[j]);
    }
    for (int off = 32; off; off >>= 1) vmax = fmaxf(vmax, __shfl_down(vmax, off));
    if (lane == 0) red[wid] = vmax;
    __syncthreads();
    float M = fmaxf(fmaxf(red[0], red[1]), fmaxf(red[2], red[3]));

    float e[4];
    float esum = 0.f;
#pragma unroll
    for (int j = 0; j < 4; j++) {
        int i = t + j * 256;
        e[j] = (i < nk) ? expf(v[j] - M) : 0.f;
        esum += e[j];
    }
    for (int off = 32; off; off >>= 1) esum += __shfl_down(esum, off);
    if (lane == 0) red[4 + wid] = esum;
    __syncthreads();
    float SUM = red[4] + red[5] + red[6] + red[7];
    __syncthreads();

    float crr = 0.f, cii = 0.f;
#pragma unroll
    for (int j = 0; j < 4; j++) {
        int i = t + j * 256;
        if (i < nk) {
            int idx = (w * (i + 1)) & (W - 1);
            float2 tt = table[idx];
            crr += e[j] * tt.x;
            cii += e[j] * tt.y;
        }
    }
    for (int off = 32; off; off >>= 1) {
        crr += __shfl_down(crr, off);
        cii += __shfl_down(cii, off);
    }
    if (lane == 0) { red[wid] = crr; red[4 + wid] = cii; }
    __syncthreads();
    float ckr = (red[0] + red[1] + red[2] + red[3]) / SUM;
    float cki = (red[4] + red[5] + red[6] + red[7]) / SUM;

#pragma unroll
    for (int k = 0; k < 4; k++) {
        size_t i = base + t + k * 256;
        v4f re = a[k] * ckr - b[k] * cki;
        v4f im = a[k] * cki + b[k] * ckr;
        __builtin_nontemporal_store(re, &((v4f*)out)[i]);
        __builtin_nontemporal_store(im, &((v4f*)out)[i + total4]);
    }
}

extern "C" void kernel_launch(void* const* d_in, const int* in_sizes, int n_in,
                              void* d_out, int out_size, void* d_ws, size_t ws_size,
                              hipStream_t stream) {
    const float* hr = (const float*)d_in[0];
    const float* hi = (const float*)d_in[1];
    const float* cr = (const float*)d_in[2];
    const float* ci = (const float*)d_in[3];
    const int* nk = (const int*)d_in[4];

    float* ws = (float*)d_ws;
    float2* table = (float2*)ws;            // [0, 8192)
    float2* nm    = (float2*)(ws + 8192);   // [8192, 16384)
    float* corr   = ws + 16384;             // [16384, 17408)
    float* out = (float*)d_out;

    void* args[] = { (void*)&hr, (void*)&hi, (void*)&cr, (void*)&ci, (void*)&nk,
                     (void*)&table, (void*)&nm, (void*)&corr, (void*)&out };
    hipError_t err = hipLaunchCooperativeKernel((const void*)fused_kernel,
                                                dim3(NBLK), dim3(256), args, 0, stream);
    if (err != hipSuccess) {
        // fallback: non-cooperative 3-kernel chain (round-2 verified)
        nm_kernel<<<W, 256, 0, stream>>>(hr, hi, cr, ci, nm, table);
        corr_kernel<<<NK_MAX, 256, 0, stream>>>(nm, table, corr, nk);
        out_kernel<<<W, 256, 0, stream>>>(hr, hi, corr, table, nk, out);
    }
}

// Round 4
// 353.482 us; speedup vs baseline: 1.6510x; 1.6510x over previous
//
#include <hip/hip_runtime.h>
#include <math.h>

#define W 4096
#define S 4096
#define NK_MAX 1024

typedef float v4f __attribute__((ext_vector_type(4)));  // clang vector — valid for nontemporal builtins

// ---------------------------------------------------------------------------
// ws layout (floats):
//   [0,     8192)  : key table float2[4096]  (cos,sin) of 2*pi*k/4096
//   [8192, 16384)  : nm    float2[4096]  (noisy_mix, interleaved re/im)
//   [16384,17408)  : corr  float[1024]
// ---------------------------------------------------------------------------
// 3-kernel chain (round-2 verified @337us): nm(+table) -> corr -> out(+ck).
// Round-3 cooperative fusion regressed 337->584 (resident-block cap + grid
// syncs destroy block-churn latency hiding) — reverted.
// This round's single change: cue loads are PLAIN (NT removed) — testing
// whether NT/slc reads throttle nm's HBM read path.
// ---------------------------------------------------------------------------

// Stage 0+1 fused: noisy_mix[w] = sum_s holo[w,s]*conj(cue[w,s]); thread 0 of
// block w computes table[w] (fp64 sincos -> exact) under the load shadow.
// One block per row: 256 threads x 4 float4 per array = 16 loads in flight
// per thread; row sum completes in one block: no atomics, direct store.
__global__ void nm_kernel(const float* __restrict__ hr, const float* __restrict__ hi,
                          const float* __restrict__ cr, const float* __restrict__ ci,
                          float2* __restrict__ nm, float2* __restrict__ table) {
    int w = blockIdx.x;
    int t = threadIdx.x;
    size_t base = (size_t)w * 1024;  // 1024 float4 per row
    const v4f* hr4 = (const v4f*)hr;
    const v4f* hi4 = (const v4f*)hi;
    const v4f* cr4 = (const v4f*)cr;
    const v4f* ci4 = (const v4f*)ci;

    v4f a[4], b[4], c[4], d[4];
#pragma unroll
    for (int k = 0; k < 4; k++) {
        size_t i = base + t + k * 256;
        a[k] = hr4[i];
        b[k] = hi4[i];
        c[k] = cr4[i];
        d[k] = ci4[i];
    }

    // table prep hidden under the load latency above
    if (t == 0) {
        double theta = (double)w * (6.283185307179586 / (double)W);
        table[w] = make_float2((float)cos(theta), (float)sin(theta));
    }

    // (hr + i*hi)(cr - i*ci): re = hr*cr + hi*ci ; im = hi*cr - hr*ci
    v4f vr = {0.f, 0.f, 0.f, 0.f}, vi = {0.f, 0.f, 0.f, 0.f};
#pragma unroll
    for (int k = 0; k < 4; k++) {
        vr += a[k] * c[k] + b[k] * d[k];
        vi += b[k] * c[k] - a[k] * d[k];
    }
    float sr = vr.x + vr.y + vr.z + vr.w;
    float si = vi.x + vi.y + vi.z + vi.w;

    for (int off = 32; off; off >>= 1) {
        sr += __shfl_down(sr, off);
        si += __shfl_down(si, off);
    }
    __shared__ float s0[4], s1[4];
    int lane = t & 63, wid = t >> 6;
    if (lane == 0) { s0[wid] = sr; s1[wid] = si; }
    __syncthreads();
    if (t == 0) {
        nm[w] = make_float2(s0[0] + s0[1] + s0[2] + s0[3],
                            s1[0] + s1[1] + s1[2] + s1[3]);
    }
}

// Stage 2: correlations[n] = |sum_w keys[n,w]*noisy_mix[w]| (no conjugation).
// One block per key; table/nm are L1/L2-hot (32 KB each).
__global__ void corr_kernel(const float2* __restrict__ nm, const float2* __restrict__ table,
                            float* __restrict__ corr, const int* __restrict__ nkp) {
    int n = blockIdx.x;
    if (n >= *nkp) return;
    int f = n + 1;
    float sr = 0.f, si = 0.f;
    for (int w = threadIdx.x; w < W; w += 256) {
        int idx = (w * f) & (W - 1);
        float2 t = table[idx];
        float2 v = nm[w];
        sr += t.x * v.x - t.y * v.y;
        si += t.x * v.y + t.y * v.x;
    }
    for (int off = 32; off; off >>= 1) {
        sr += __shfl_down(sr, off);
        si += __shfl_down(si, off);
    }
    __shared__ float s0[4], s1[4];
    int lane = threadIdx.x & 63, wid = threadIdx.x >> 6;
    if (lane == 0) { s0[wid] = sr; s1[wid] = si; }
    __syncthreads();
    if (threadIdx.x == 0) {
        float r = s0[0] + s0[1] + s0[2] + s0[3];
        float m = s1[0] + s1[1] + s1[2] + s1[3];
        corr[n] = sqrtf(r * r + m * m);
    }
}

// Stage 3+4+5 fused: one block per row. Row loads issued FIRST; softmax
// (deterministic, identical per block) + this row's clean_key computed under
// their latency; then the row is streamed out with NT stores (write-once).
__global__ void out_kernel(const float* __restrict__ hr, const float* __restrict__ hi,
                           const float* __restrict__ corr, const float2* __restrict__ table,
                           const int* __restrict__ nkp, float* __restrict__ out) {
    int w = blockIdx.x;
    int t = threadIdx.x;
    size_t base = (size_t)w * 1024;  // 1024 float4 per row
    const size_t total4 = (size_t)W * S / 4;
    int lane = t & 63, wid = t >> 6;
    __shared__ float red[8];

    // issue the row's streaming loads before any compute
    v4f a[4], b[4];
#pragma unroll
    for (int k = 0; k < 4; k++) {
        size_t i = base + t + k * 256;
        a[k] = ((const v4f*)hr)[i];
        b[k] = ((const v4f*)hi)[i];
    }

    int nk = *nkp;

    // --- block softmax over corr[0..nk) ---
    float v[4];
    float vmax = -INFINITY;
#pragma unroll
    for (int j = 0; j < 4; j++) {
        int i = t + j * 256;
        v[j] = (i < nk) ? corr[i] * 50.0f : -INFINITY;
        vmax = fmaxf(vmax, v[j]);
    }
    for (int off = 32; off; off >>= 1) vmax = fmaxf(vmax, __shfl_down(vmax, off));
    if (lane == 0) red[wid] = vmax;
    __syncthreads();
    float M = fmaxf(fmaxf(red[0], red[1]), fmaxf(red[2], red[3]));

    float e[4];
    float esum = 0.f;
#pragma unroll
    for (int j = 0; j < 4; j++) {
        int i = t + j * 256;
        e[j] = (i < nk) ? expf(v[j] - M) : 0.f;
        esum += e[j];
    }
    for (int off = 32; off; off >>= 1) esum += __shfl_down(esum, off);
    if (lane == 0) red[4 + wid] = esum;
    __syncthreads();
    float SUM = red[4] + red[5] + red[6] + red[7];
    __syncthreads();  // red about to be reused

    // --- this row's clean_key: 4 keys per thread, table reads L1/L2-hot ---
    float crr = 0.f, cii = 0.f;
#pragma unroll
    for (int j = 0; j < 4; j++) {
        int i = t + j * 256;
        if (i < nk) {
            int idx = (w * (i + 1)) & (W - 1);
            float2 tt = table[idx];
            crr += e[j] * tt.x;
            cii += e[j] * tt.y;
        }
    }
    for (int off = 32; off; off >>= 1) {
        crr += __shfl_down(crr, off);
        cii += __shfl_down(cii, off);
    }
    if (lane == 0) { red[wid] = crr; red[4 + wid] = cii; }
    __syncthreads();
    float ckr = (red[0] + red[1] + red[2] + red[3]) / SUM;
    float cki = (red[4] + red[5] + red[6] + red[7]) / SUM;

    // --- stream the row ---
#pragma unroll
    for (int k = 0; k < 4; k++) {
        size_t i = base + t + k * 256;
        v4f re = a[k] * ckr - b[k] * cki;
        v4f im = a[k] * cki + b[k] * ckr;
        __builtin_nontemporal_store(re, &((v4f*)out)[i]);
        __builtin_nontemporal_store(im, &((v4f*)out)[i + total4]);
    }
}

extern "C" void kernel_launch(void* const* d_in, const int* in_sizes, int n_in,
                              void* d_out, int out_size, void* d_ws, size_t ws_size,
                              hipStream_t stream) {
    const float* hr = (const float*)d_in[0];
    const float* hi = (const float*)d_in[1];
    const float* cr = (const float*)d_in[2];
    const float* ci = (const float*)d_in[3];
    const int* nk = (const int*)d_in[4];

    float* ws = (float*)d_ws;
    float2* table = (float2*)ws;            // [0, 8192)
    float2* nm    = (float2*)(ws + 8192);   // [8192, 16384)
    float* corr   = ws + 16384;             // [16384, 17408)
    float* out = (float*)d_out;

    nm_kernel<<<W, 256, 0, stream>>>(hr, hi, cr, ci, nm, table);
    corr_kernel<<<NK_MAX, 256, 0, stream>>>(nm, table, corr, nk);
    out_kernel<<<W, 256, 0, stream>>>(hr, hi, corr, table, nk, out);
}

// Round 5
// 346.472 us; speedup vs baseline: 1.6844x; 1.0202x over previous
//
#include <hip/hip_runtime.h>
#include <math.h>

#define W 4096
#define S 4096
#define NK_MAX 1024

typedef float v4f __attribute__((ext_vector_type(4)));  // clang vector — valid for nontemporal builtins

// ---------------------------------------------------------------------------
// ws layout (floats):
//   [0,     8192)  : key table float2[4096]  (cos,sin) of 2*pi*k/4096
//   [8192, 16384)  : nm    float2[4096]  (noisy_mix, interleaved re/im)
//   [16384,17408)  : corr  float[1024]
// ---------------------------------------------------------------------------
// 3-kernel chain: nm(+table) -> corr -> out(+softmax+ck).
// R3 lesson: cooperative fusion regresses (resident-block cap + grid syncs).
// R4 lesson: NT cue loads are a ~25us win (keep holo L3-resident) — restored.
// R5 change: wave-per-row in nm/out (1024 blocks x 4 waves, shuffle-only
// reduce, no __syncthreads in the streaming path) -> more independent load
// streams per CU, 4x less block churn, softmax amortized 4x in out.
// ---------------------------------------------------------------------------

// Stage 0+1: noisy_mix[w] = sum_s holo[w,s]*conj(cue[w,s]).
// One WAVE per row, 4 chunks x 4 float4 per array per lane; pure shuffle
// reduce; lane 0 stores. Threads 0..3 also write this block's 4 table entries
// (fp64 sincos -> exact), hidden under the load shadow.
__global__ void nm_kernel(const float* __restrict__ hr, const float* __restrict__ hi,
                          const float* __restrict__ cr, const float* __restrict__ ci,
                          float2* __restrict__ nm, float2* __restrict__ table) {
    int t = threadIdx.x;
    int lane = t & 63, wid = t >> 6;
    int bid = blockIdx.x;
    const v4f* hr4 = (const v4f*)hr;
    const v4f* hi4 = (const v4f*)hi;
    const v4f* cr4 = (const v4f*)cr;
    const v4f* ci4 = (const v4f*)ci;

    if (t < 4) {
        int k = bid * 4 + t;
        double theta = (double)k * (6.283185307179586 / (double)W);
        table[k] = make_float2((float)cos(theta), (float)sin(theta));
    }

    int w = bid * 4 + wid;              // this wave's row
    size_t base = (size_t)w * 1024;     // 1024 float4 per row

    v4f vr = {0.f, 0.f, 0.f, 0.f}, vi = {0.f, 0.f, 0.f, 0.f};
#pragma unroll 1
    for (int ch = 0; ch < 4; ch++) {
        v4f a[4], b[4], c[4], d[4];
#pragma unroll
        for (int k = 0; k < 4; k++) {
            size_t i = base + ch * 256 + k * 64 + lane;
            a[k] = hr4[i];
            b[k] = hi4[i];
            c[k] = __builtin_nontemporal_load(&cr4[i]);   // cue is single-use
            d[k] = __builtin_nontemporal_load(&ci4[i]);
        }
        // (hr + i*hi)(cr - i*ci): re = hr*cr + hi*ci ; im = hi*cr - hr*ci
#pragma unroll
        for (int k = 0; k < 4; k++) {
            vr += a[k] * c[k] + b[k] * d[k];
            vi += b[k] * c[k] - a[k] * d[k];
        }
    }
    float sr = vr.x + vr.y + vr.z + vr.w;
    float si = vi.x + vi.y + vi.z + vi.w;
    for (int off = 32; off; off >>= 1) {
        sr += __shfl_down(sr, off);
        si += __shfl_down(si, off);
    }
    if (lane == 0) nm[w] = make_float2(sr, si);
}

// Stage 2: correlations[n] = |sum_w keys[n,w]*noisy_mix[w]| (no conjugation).
// One block per key; table/nm are L1/L2-hot (32 KB each).
__global__ void corr_kernel(const float2* __restrict__ nm, const float2* __restrict__ table,
                            float* __restrict__ corr, const int* __restrict__ nkp) {
    int n = blockIdx.x;
    if (n >= *nkp) return;
    int f = n + 1;
    float sr = 0.f, si = 0.f;
    for (int w = threadIdx.x; w < W; w += 256) {
        int idx = (w * f) & (W - 1);
        float2 t = table[idx];
        float2 v = nm[w];
        sr += t.x * v.x - t.y * v.y;
        si += t.x * v.y + t.y * v.x;
    }
    for (int off = 32; off; off >>= 1) {
        sr += __shfl_down(sr, off);
        si += __shfl_down(si, off);
    }
    __shared__ float s0[4], s1[4];
    int lane = threadIdx.x & 63, wid = threadIdx.x >> 6;
    if (lane == 0) { s0[wid] = sr; s1[wid] = si; }
    __syncthreads();
    if (threadIdx.x == 0) {
        float r = s0[0] + s0[1] + s0[2] + s0[3];
        float m = s1[0] + s1[1] + s1[2] + s1[3];
        corr[n] = sqrtf(r * r + m * m);
    }
}

// Stage 3+4+5: 1024 blocks. Block softmax ONCE (amortized over 4 rows, satt
// in LDS), then each wave independently computes its row's clean_key
// (ck_w = sum_n att[n] * table[(w*(n+1)) & 4095], table L1-hot) and streams
// the row: out[0,w,s] = hr*ckr - hi*cki ; out[1,w,s] = hr*cki + hi*ckr.
// NT stores: output written once, never re-read on device.
__global__ void out_kernel(const float* __restrict__ hr, const float* __restrict__ hi,
                           const float* __restrict__ corr, const float2* __restrict__ table,
                           const int* __restrict__ nkp, float* __restrict__ out) {
    __shared__ float satt[NK_MAX];   // unnormalized softmax weights
    __shared__ float red[8];
    int t = threadIdx.x;
    int lane = t & 63, wid = t >> 6;
    int bid = blockIdx.x;
    int nk = *nkp;
    const v4f* hr4 = (const v4f*)hr;
    const v4f* hi4 = (const v4f*)hi;

    // --- block softmax over corr[0..nk) (corr is L2-hot, 4 KB) ---
    float v[4];
    float vmax = -INFINITY;
#pragma unroll
    for (int j = 0; j < 4; j++) {
        int i = t + j * 256;
        v[j] = (i < nk) ? corr[i] * 50.0f : -INFINITY;
        vmax = fmaxf(vmax, v[j]);
    }
    for (int off = 32; off; off >>= 1) vmax = fmaxf(vmax, __shfl_down(vmax, off));
    if (lane == 0) red[wid] = vmax;
    __syncthreads();
    float M = fmaxf(fmaxf(red[0], red[1]), fmaxf(red[2], red[3]));

    float esum = 0.f;
#pragma unroll
    for (int j = 0; j < 4; j++) {
        int i = t + j * 256;
        float e = (i < nk) ? expf(v[j] - M) : 0.f;
        satt[i] = e;   // unnormalized; divide by SUM at the end (linear op)
        esum += e;
    }
    for (int off = 32; off; off >>= 1) esum += __shfl_down(esum, off);
    if (lane == 0) red[4 + wid] = esum;
    __syncthreads();   // satt + red visible
    float SUM = red[4] + red[5] + red[6] + red[7];

    // --- wave-independent from here: clean_key for this wave's row ---
    int w = bid * 4 + wid;
    size_t base = (size_t)w * 1024;
    const size_t total4 = (size_t)W * S / 4;

    float crr = 0.f, cii = 0.f;
#pragma unroll 4
    for (int k = 0; k < 16; k++) {
        int n = lane + k * 64;
        int idx = (w * (n + 1)) & (W - 1);
        float2 tt = table[idx];   // L1-hot 32 KB
        float a = satt[n];        // 0 for n >= nk
        crr += a * tt.x;
        cii += a * tt.y;
    }
    for (int off = 32; off; off >>= 1) {
        crr += __shfl_down(crr, off);
        cii += __shfl_down(cii, off);
    }
    float ckr = __shfl(crr, 0) / SUM;
    float cki = __shfl(cii, 0) / SUM;

    // --- stream the row (hr/hi are L3-hot after nm) ---
#pragma unroll 1
    for (int ch = 0; ch < 4; ch++) {
        v4f a[4], b[4];
#pragma unroll
        for (int k = 0; k < 4; k++) {
            size_t i = base + ch * 256 + k * 64 + lane;
            a[k] = hr4[i];
            b[k] = hi4[i];
        }
#pragma unroll
        for (int k = 0; k < 4; k++) {
            size_t i = base + ch * 256 + k * 64 + lane;
            v4f re = a[k] * ckr - b[k] * cki;
            v4f im = a[k] * cki + b[k] * ckr;
            __builtin_nontemporal_store(re, &((v4f*)out)[i]);
            __builtin_nontemporal_store(im, &((v4f*)out)[i + total4]);
        }
    }
}

extern "C" void kernel_launch(void* const* d_in, const int* in_sizes, int n_in,
                              void* d_out, int out_size, void* d_ws, size_t ws_size,
                              hipStream_t stream) {
    const float* hr = (const float*)d_in[0];
    const float* hi = (const float*)d_in[1];
    const float* cr = (const float*)d_in[2];
    const float* ci = (const float*)d_in[3];
    const int* nk = (const int*)d_in[4];

    float* ws = (float*)d_ws;
    float2* table = (float2*)ws;            // [0, 8192)
    float2* nm    = (float2*)(ws + 8192);   // [8192, 16384)
    float* corr   = ws + 16384;             // [16384, 17408)
    float* out = (float*)d_out;

    nm_kernel<<<W / 4, 256, 0, stream>>>(hr, hi, cr, ci, nm, table);
    corr_kernel<<<NK_MAX, 256, 0, stream>>>(nm, table, corr, nk);
    out_kernel<<<W / 4, 256, 0, stream>>>(hr, hi, corr, table, nk, out);
}